// Round 1
// baseline (783.733 us; speedup 1.0000x reference)
//
#include <hip/hip_runtime.h>
#include <hip/hip_bf16.h>
#include <math.h>

// H=2048 NH=16 NG=4 WS=256 SS=128 B=2 N=4096 C=512 HD=32
// out0: (2,4096,2048) f32 = 16,777,216 elems
// out1 attn: (4,16,2,16,256,256) f32 = 134,217,728 elems
// ws needed ~127 MB

typedef short bf16x8 __attribute__((ext_vector_type(8)));
typedef float f32x4 __attribute__((ext_vector_type(4)));

#define AS1 __attribute__((address_space(1)))
#define AS3 __attribute__((address_space(3)))

__device__ __forceinline__ void gload16(const void* g, void* l) {
  __builtin_amdgcn_global_load_lds((const AS1 void*)g, (AS3 void*)l, 16, 0, 0);
}

__device__ __forceinline__ unsigned short f2bf(float f) {
  unsigned u = __float_as_uint(f);
  u += 0x7FFFu + ((u >> 16) & 1u);
  return (unsigned short)(u >> 16);
}

// ---- RoPE tables: cos/sin[(p, idx)] for p<4096, idx<256 ----
__global__ __launch_bounds__(256) void k_tables(float* __restrict__ cosT, float* __restrict__ sinT) {
  int t = blockIdx.x * 256 + threadIdx.x;
  int p = t >> 8, idx = t & 255;
  float invf = (float)exp2(-(double)idx * (13.287712379549449 / 256.0)); // 10000^(-idx/256)
  float ang = (float)p * invf;
  float s, c;
  sincosf(ang, &s, &c);
  cosT[t] = c;
  sinT[t] = s;
}

// ---- f32 -> bf16 (4 per thread) ----
__global__ __launch_bounds__(256) void k_conv(const float* __restrict__ in,
                                              unsigned short* __restrict__ out, int n4) {
  int i = blockIdx.x * 256 + threadIdx.x;
  if (i >= n4) return;
  float4 v = ((const float4*)in)[i];
  ushort4 o = make_ushort4(f2bf(v.x), f2bf(v.y), f2bf(v.z), f2bf(v.w));
  ((ushort4*)out)[i] = o;
}

// ---- transpose+convert: in f32 [R][C] -> out bf16 [rowOff+C][R] (out stride R) ----
__global__ __launch_bounds__(256) void k_transpose(const float* __restrict__ in,
                                                   unsigned short* __restrict__ out,
                                                   int R, int C, int rowOff) {
  __shared__ float tile[32][33];
  int tc = blockIdx.x * 32, tr = blockIdx.y * 32;
  int lx = threadIdx.x & 31, ly = threadIdx.x >> 5;
#pragma unroll
  for (int s2 = 0; s2 < 4; ++s2) {
    int rr = ly + s2 * 8;
    tile[rr][lx] = in[(size_t)(tr + rr) * C + tc + lx];
  }
  __syncthreads();
#pragma unroll
  for (int s2 = 0; s2 < 4; ++s2) {
    int cc = ly + s2 * 8;
    out[(size_t)(rowOff + tc + cc) * R + tr + lx] = f2bf(tile[lx][cc]);
  }
}

__global__ void k_biaskv(const float* __restrict__ bk, const float* __restrict__ bv,
                         float* __restrict__ o) {
  int n = threadIdx.x;  // 128 threads
  o[n] = (n < 32) ? bk[n] : ((n < 64) ? bv[n - 32] : 0.f);
}

// ---- bf16 MFMA GEMM: A[M][K] bf16, Bt[N][K] bf16, C[M][N] f32 (+bias[col]) ----
// BK=32, 256 threads = 4 waves as 2x2, m97-style single-buffer 2-barrier loop.
template <int BM, int BN>
__global__ __launch_bounds__(256) void k_gemm(const unsigned short* __restrict__ A,
                                              const unsigned short* __restrict__ Bt,
                                              float* __restrict__ C,
                                              const float* __restrict__ bias,
                                              int M, int N, int K) {
  __shared__ unsigned short Al[BM * 32];
  __shared__ unsigned short Bl[BN * 32];
  const int tid = threadIdx.x;
  const int wave = tid >> 6, lane = tid & 63;
  const int wm = wave >> 1, wn = wave & 1;
  constexpr int FM = BM / 32, FN = BN / 32;
  f32x4 acc[FM][FN] = {};
  const int lrow = lane & 15, kq = (lane >> 4) * 8;
  const size_t abase = (size_t)blockIdx.x * BM;
  const size_t bbase = (size_t)blockIdx.y * BN;
  const int rA = lane >> 2, cA = (lane & 3) * 8;

  for (int kt = 0; kt < K; kt += 32) {
#pragma unroll
    for (int c2 = 0; c2 < BM / 64; ++c2) {
      int rr = (c2 * 4 + wave) * 16 + rA;
      gload16(A + (abase + rr) * K + kt + cA, Al + (c2 * 4 + wave) * 512);
    }
#pragma unroll
    for (int c2 = 0; c2 < BN / 64; ++c2) {
      int rr = (c2 * 4 + wave) * 16 + rA;
      gload16(Bt + (bbase + rr) * K + kt + cA, Bl + (c2 * 4 + wave) * 512);
    }
    __syncthreads();  // drains vmcnt before barrier (compiler-emitted)
    bf16x8 af[FM], bg[FN];
#pragma unroll
    for (int m = 0; m < FM; ++m)
      af[m] = *(const bf16x8*)&Al[(wm * (BM / 2) + m * 16 + lrow) * 32 + kq];
#pragma unroll
    for (int n = 0; n < FN; ++n)
      bg[n] = *(const bf16x8*)&Bl[(wn * (BN / 2) + n * 16 + lrow) * 32 + kq];
#pragma unroll
    for (int m = 0; m < FM; ++m)
#pragma unroll
      for (int n = 0; n < FN; ++n)
        acc[m][n] = __builtin_amdgcn_mfma_f32_16x16x32_bf16(af[m], bg[n], acc[m][n], 0, 0, 0);
    __syncthreads();
  }
  const int mb = blockIdx.x * BM + wm * (BM / 2);
  const int nb = blockIdx.y * BN + wn * (BN / 2);
#pragma unroll
  for (int m = 0; m < FM; ++m)
#pragma unroll
    for (int n = 0; n < FN; ++n)
#pragma unroll
      for (int r2 = 0; r2 < 4; ++r2) {
        int row = mb + m * 16 + (lane >> 4) * 4 + r2;
        int col = nb + n * 16 + lrow;
        C[(size_t)row * N + col] = acc[m][n][r2] + bias[col];
      }
}

// ---- attention: one block per (g,w,b,h); 256 threads, thread i owns row i ----
__global__ __launch_bounds__(256) void k_attn(const float* __restrict__ qbuf,
                                              const float* __restrict__ kvbuf,
                                              const float* __restrict__ cosT,
                                              const float* __restrict__ sinT,
                                              float* __restrict__ attn_out,
                                              unsigned short* __restrict__ cv) {
  __shared__ float Ks[256 * 32];
  __shared__ float Pt[256 * 33];
  __shared__ float qraw[16][32], kraw[16][32], vraw[16][32];
  const int t = threadIdx.x;
  const int unit = blockIdx.x;
  const int h = unit & 15, b = (unit >> 4) & 1, w = (unit >> 5) & 15, g = unit >> 9;
  const int row0 = b * 4096 + w * 256 + 16 * h;  // global (B*N) row base
  const int p0 = w * 256 + 16 * h;               // rope position base

  for (int e = t; e < 512; e += 256) {
    int r = e >> 5, ch = e & 31;
    size_t gi = (size_t)(row0 + r) * 128;
    qraw[r][ch] = qbuf[gi + g * 32 + ch];
    kraw[r][ch] = kvbuf[gi + ch];
    vraw[r][ch] = kvbuf[gi + 32 + ch];
  }
  __syncthreads();

  // build K~ row t (into LDS) and Q~ row t (into regs, pre-scaled by 1/sqrt(512))
  float Qrow[32];
  {
    const int r = t >> 4, cb = t & 15;
    const int ch = 2 * cb;
    const int po = (cb < 8) ? 16 : -16;
    const float sg = (cb < 8) ? -1.f : 1.f;
    const float4* c4 = (const float4*)(cosT + (size_t)(p0 + r) * 256 + 32 * (cb & 7));
    const float4* s4 = (const float4*)(sinT + (size_t)(p0 + r) * 256 + 32 * (cb & 7));
    float qa0 = qraw[r][ch], qa1 = qraw[r][ch + 1];
    float qp0 = qraw[r][ch + po], qp1 = qraw[r][ch + po + 1];
    float ka0 = kraw[r][ch], ka1 = kraw[r][ch + 1];
    float kp0 = kraw[r][ch + po], kp1 = kraw[r][ch + po + 1];
    const float rs = 0.044194173824159216f;  // 1/sqrt(512)
#pragma unroll
    for (int dq = 0; dq < 8; ++dq) {
      float4 cc = c4[dq], ss = s4[dq];
      float qa = (dq < 4) ? qa0 : qa1, qp = (dq < 4) ? qp0 : qp1;
      float ka = (dq < 4) ? ka0 : ka1, kp = (dq < 4) ? kp0 : kp1;
      Qrow[dq * 4 + 0] = (qa * cc.x + sg * qp * ss.x) * rs;
      Qrow[dq * 4 + 1] = (qa * cc.y + sg * qp * ss.y) * rs;
      Qrow[dq * 4 + 2] = (qa * cc.z + sg * qp * ss.z) * rs;
      Qrow[dq * 4 + 3] = (qa * cc.w + sg * qp * ss.w) * rs;
      Ks[t * 32 + dq * 4 + 0] = ka * cc.x + sg * kp * ss.x;
      Ks[t * 32 + dq * 4 + 1] = ka * cc.y + sg * kp * ss.y;
      Ks[t * 32 + dq * 4 + 2] = ka * cc.z + sg * kp * ss.z;
      Ks[t * 32 + dq * 4 + 3] = ka * cc.w + sg * kp * ss.w;
    }
  }
  __syncthreads();

  const int i = t;
  const int jmaxw = ((t >> 6) + 1) << 6;  // wave-uniform: rows of wave wv are < 64*(wv+1)

  // pass A: online softmax stats (masked entries are 0, NOT -inf)
  float mrun = -INFINITY, lrun = 0.f;
  for (int j = 0; j < jmaxw; ++j) {
    const float4* kr = (const float4*)&Ks[j * 32];
    float a0 = 0, a1 = 0, a2 = 0, a3 = 0;
#pragma unroll
    for (int dq = 0; dq < 8; ++dq) {
      float4 kk = kr[dq];
      a0 += Qrow[dq * 4 + 0] * kk.x;
      a1 += Qrow[dq * 4 + 1] * kk.y;
      a2 += Qrow[dq * 4 + 2] * kk.z;
      a3 += Qrow[dq * 4 + 3] * kk.w;
    }
    float s = (a0 + a1) + (a2 + a3);
    float sp = (j <= i) ? s : 0.f;
    float mn = fmaxf(mrun, sp);
    lrun = lrun * __expf(mrun - mn) + __expf(sp - mn);
    mrun = mn;
  }
  if (jmaxw < 256) {  // analytic tail: (256-jmaxw) masked zeros
    float mn = fmaxf(mrun, 0.f);
    lrun = lrun * __expf(mrun - mn) + (float)(256 - jmaxw) * __expf(0.f - mn);
    mrun = mn;
  }
  const float invl = 1.f / lrun;
  const float pz = __expf(-mrun) * invl;

  // pass B: probabilities + PV (V~ has only 2 distinct values per j!)
  float ava = 0.f, avb = 0.f;
  for (int j = 0; j < 256; ++j) {
    float p;
    if (j < jmaxw) {  // wave-uniform branch
      const float4* kr = (const float4*)&Ks[j * 32];
      float a0 = 0, a1 = 0, a2 = 0, a3 = 0;
#pragma unroll
      for (int dq = 0; dq < 8; ++dq) {
        float4 kk = kr[dq];
        a0 += Qrow[dq * 4 + 0] * kk.x;
        a1 += Qrow[dq * 4 + 1] * kk.y;
        a2 += Qrow[dq * 4 + 2] * kk.z;
        a3 += Qrow[dq * 4 + 3] * kk.w;
      }
      float s = (a0 + a1) + (a2 + a3);
      float sp = (j <= i) ? s : 0.f;
      p = __expf(sp - mrun) * invl;
    } else {
      p = pz;
    }
    Pt[i * 33 + (j & 31)] = p;
    float va = vraw[j >> 4][(j & 15) * 2], vb = vraw[j >> 4][(j & 15) * 2 + 1];
    ava += p * va;
    avb += p * vb;
    if ((j & 31) == 31) {  // coalesced flush of 256x32 chunk
      __syncthreads();
      const int j0 = j & ~31;
      const size_t base = (size_t)unit * 65536 + j0;
#pragma unroll
      for (int It = 0; It < 32; ++It) {
        int flat = It * 256 + t;
        int rr = flat >> 5, ccol = flat & 31;
        attn_out[base + (size_t)rr * 256 + ccol] = Pt[rr * 33 + ccol];
      }
      __syncthreads();
    }
  }

  // merged[b, w*256+i, g*512 + h*32 + d]; d<16 -> ava, else avb (roll is identity)
  unsigned short* cp = cv + (size_t)(b * 4096 + w * 256 + i) * 2048 + g * 512 + h * 32;
  unsigned short aa = f2bf(ava), ab = f2bf(avb);
#pragma unroll
  for (int d = 0; d < 16; ++d) cp[d] = aa;
#pragma unroll
  for (int d = 16; d < 32; ++d) cp[d] = ab;
}

extern "C" void kernel_launch(void* const* d_in, const int* in_sizes, int n_in,
                              void* d_out, int out_size, void* d_ws, size_t ws_size,
                              hipStream_t stream) {
  const float* inputs  = (const float*)d_in[0];
  const float* context = (const float*)d_in[1];
  const float* Wq = (const float*)d_in[3];
  const float* bq = (const float*)d_in[4];
  const float* Wk = (const float*)d_in[5];
  const float* bk = (const float*)d_in[6];
  const float* Wv = (const float*)d_in[7];
  const float* bv = (const float*)d_in[8];
  const float* Wo = (const float*)d_in[9];
  const float* bo = (const float*)d_in[10];
  float* out = (float*)d_out;
  float* attn_out = out + 16777216;  // second output region

  char* wsb = (char*)d_ws;
  size_t o = 0;
  float* cosT = (float*)(wsb + o);            o += 4194304;
  float* sinT = (float*)(wsb + o);            o += 4194304;
  unsigned short* inb  = (unsigned short*)(wsb + o); o += 33554432;
  unsigned short* ctxb = (unsigned short*)(wsb + o); o += 33554432;
  unsigned short* WqT  = (unsigned short*)(wsb + o); o += 524288;
  unsigned short* WkvT = (unsigned short*)(wsb + o); o += 524288;
  unsigned short* WoT  = (unsigned short*)(wsb + o); o += 8388608;
  float* qbuf  = (float*)(wsb + o);           o += 4194304;
  float* kvbuf = (float*)(wsb + o);           o += 4194304;
  unsigned short* cvb = (unsigned short*)(wsb + o); o += 33554432;
  float* biaskv = (float*)(wsb + o);          o += 512;

  k_tables<<<4096, 256, 0, stream>>>(cosT, sinT);
  k_conv<<<16384, 256, 0, stream>>>(inputs, inb, 4194304);
  k_conv<<<16384, 256, 0, stream>>>(context, ctxb, 4194304);
  k_transpose<<<dim3(4, 64), 256, 0, stream>>>(Wq, WqT, 2048, 128, 0);
  k_transpose<<<dim3(1, 64), 256, 0, stream>>>(Wk, WkvT, 2048, 32, 0);
  k_transpose<<<dim3(1, 64), 256, 0, stream>>>(Wv, WkvT, 2048, 32, 32);
  k_transpose<<<dim3(64, 64), 256, 0, stream>>>(Wo, WoT, 2048, 2048, 0);
  hipMemsetAsync(WkvT + 64 * 2048, 0, 64 * 2048 * 2, stream);
  k_biaskv<<<1, 128, 0, stream>>>(bk, bv, biaskv);

  // q = inputs @ Wq (+bq): M=8192 N=128 K=2048
  k_gemm<64, 64><<<dim3(128, 2), 256, 0, stream>>>(inb, WqT, qbuf, bq, 8192, 128, 2048);
  // kv = context @ [Wk|Wv|0] (+[bk|bv|0])
  k_gemm<64, 64><<<dim3(128, 2), 256, 0, stream>>>(ctxb, WkvT, kvbuf, biaskv, 8192, 128, 2048);

  k_attn<<<2048, 256, 0, stream>>>(qbuf, kvbuf, cosT, sinT, attn_out, cvb);

  // out = cv @ Wo + bo: M=8192 N=2048 K=2048
  k_gemm<128, 128><<<dim3(64, 16), 256, 0, stream>>>(cvb, WoT, out, bo, 8192, 2048, 2048);
}

// Round 2
// 385.095 us; speedup vs baseline: 2.0352x; 2.0352x over previous
//
#include <hip/hip_runtime.h>
#include <hip/hip_bf16.h>
#include <math.h>

// H=2048 NH=16 NG=4 WS=256 SS=128 B=2 N=4096 C=512 HD=32
// out0: (2,4096,2048) f32 ; out1 attn: (4,16,2,16,256,256) f32

typedef short bf16x8 __attribute__((ext_vector_type(8)));
typedef float f32x4 __attribute__((ext_vector_type(4)));
typedef unsigned short u16x8 __attribute__((ext_vector_type(8)));

#define AS1 __attribute__((address_space(1)))
#define AS3 __attribute__((address_space(3)))

__device__ __forceinline__ void gload16(const void* g, void* l) {
  __builtin_amdgcn_global_load_lds((const AS1 void*)g, (AS3 void*)l, 16, 0, 0);
}

__device__ __forceinline__ unsigned short f2bf(float f) {
  unsigned u = __float_as_uint(f);
  u += 0x7FFFu + ((u >> 16) & 1u);
  return (unsigned short)(u >> 16);
}

// ---- RoPE tables: cos/sin[(p, idx)] for p<4096, idx<256 ----
__global__ __launch_bounds__(256) void k_tables(float* __restrict__ cosT, float* __restrict__ sinT) {
  int t = blockIdx.x * 256 + threadIdx.x;
  int p = t >> 8, idx = t & 255;
  float invf = (float)exp2(-(double)idx * (13.287712379549449 / 256.0)); // 10000^(-idx/256)
  float ang = (float)p * invf;
  float s, c;
  sincosf(ang, &s, &c);
  cosT[t] = c;
  sinT[t] = s;
}

// ---- f32 -> bf16 (4 per thread) ----
__global__ __launch_bounds__(256) void k_conv(const float* __restrict__ in,
                                              unsigned short* __restrict__ out, int n4) {
  int i = blockIdx.x * 256 + threadIdx.x;
  if (i >= n4) return;
  float4 v = ((const float4*)in)[i];
  ushort4 o = make_ushort4(f2bf(v.x), f2bf(v.y), f2bf(v.z), f2bf(v.w));
  ((ushort4*)out)[i] = o;
}

// ---- transpose+convert: in f32 [R][C] -> out bf16 [rowOff+C][R] (out stride R) ----
__global__ __launch_bounds__(256) void k_transpose(const float* __restrict__ in,
                                                   unsigned short* __restrict__ out,
                                                   int R, int C, int rowOff) {
  __shared__ float tile[32][33];
  int tc = blockIdx.x * 32, tr = blockIdx.y * 32;
  int lx = threadIdx.x & 31, ly = threadIdx.x >> 5;
#pragma unroll
  for (int s2 = 0; s2 < 4; ++s2) {
    int rr = ly + s2 * 8;
    tile[rr][lx] = in[(size_t)(tr + rr) * C + tc + lx];
  }
  __syncthreads();
#pragma unroll
  for (int s2 = 0; s2 < 4; ++s2) {
    int cc = ly + s2 * 8;
    out[(size_t)(rowOff + tc + cc) * R + tr + lx] = f2bf(tile[lx][cc]);
  }
}

__global__ void k_biaskv(const float* __restrict__ bk, const float* __restrict__ bv,
                         float* __restrict__ o) {
  int n = threadIdx.x;  // 128 threads
  o[n] = (n < 32) ? bk[n] : ((n < 64) ? bv[n - 32] : 0.f);
}

// ---- bf16 MFMA GEMM: A[M][K] bf16, Bt[N][K] bf16, C[M][N] f32 (+bias[col]) ----
template <int BM, int BN>
__global__ __launch_bounds__(256) void k_gemm(const unsigned short* __restrict__ A,
                                              const unsigned short* __restrict__ Bt,
                                              float* __restrict__ C,
                                              const float* __restrict__ bias,
                                              int M, int N, int K) {
  __shared__ unsigned short Al[BM * 32];
  __shared__ unsigned short Bl[BN * 32];
  const int tid = threadIdx.x;
  const int wave = tid >> 6, lane = tid & 63;
  const int wm = wave >> 1, wn = wave & 1;
  constexpr int FM = BM / 32, FN = BN / 32;
  f32x4 acc[FM][FN] = {};
  const int lrow = lane & 15, kq = (lane >> 4) * 8;
  const size_t abase = (size_t)blockIdx.x * BM;
  const size_t bbase = (size_t)blockIdx.y * BN;
  const int rA = lane >> 2, cA = (lane & 3) * 8;

  for (int kt = 0; kt < K; kt += 32) {
#pragma unroll
    for (int c2 = 0; c2 < BM / 64; ++c2) {
      int rr = (c2 * 4 + wave) * 16 + rA;
      gload16(A + (abase + rr) * K + kt + cA, Al + (c2 * 4 + wave) * 512);
    }
#pragma unroll
    for (int c2 = 0; c2 < BN / 64; ++c2) {
      int rr = (c2 * 4 + wave) * 16 + rA;
      gload16(Bt + (bbase + rr) * K + kt + cA, Bl + (c2 * 4 + wave) * 512);
    }
    __syncthreads();
    bf16x8 af[FM], bg[FN];
#pragma unroll
    for (int m = 0; m < FM; ++m)
      af[m] = *(const bf16x8*)&Al[(wm * (BM / 2) + m * 16 + lrow) * 32 + kq];
#pragma unroll
    for (int n = 0; n < FN; ++n)
      bg[n] = *(const bf16x8*)&Bl[(wn * (BN / 2) + n * 16 + lrow) * 32 + kq];
#pragma unroll
    for (int m = 0; m < FM; ++m)
#pragma unroll
      for (int n = 0; n < FN; ++n)
        acc[m][n] = __builtin_amdgcn_mfma_f32_16x16x32_bf16(af[m], bg[n], acc[m][n], 0, 0, 0);
    __syncthreads();
  }
  const int mb = blockIdx.x * BM + wm * (BM / 2);
  const int nb = blockIdx.y * BN + wn * (BN / 2);
#pragma unroll
  for (int m = 0; m < FM; ++m)
#pragma unroll
    for (int n = 0; n < FN; ++n)
#pragma unroll
      for (int r2 = 0; r2 < 4; ++r2) {
        int row = mb + m * 16 + (lane >> 4) * 4 + r2;
        int col = nb + n * 16 + lrow;
        C[(size_t)row * N + col] = acc[m][n][r2] + bias[col];
      }
}

// ---- attention: one block per (g,w,b,h); 256 threads = 4 waves ----
// S = Q~ K~^T via MFMA (bf16), single-pass softmax in registers.
__global__ __launch_bounds__(256) void k_attn(const float* __restrict__ qbuf,
                                              const float* __restrict__ kvbuf,
                                              const float* __restrict__ cosT,
                                              const float* __restrict__ sinT,
                                              float* __restrict__ attn_out,
                                              unsigned short* __restrict__ cv) {
  __shared__ unsigned short Qb[256 * 32];  // bf16, pre-scaled by 1/sqrt(512)
  __shared__ unsigned short Kb[256 * 32];  // bf16
  __shared__ float qraw[16][32], kraw[16][32], vraw[16][32];
  const int t = threadIdx.x;
  const int unit = blockIdx.x;
  const int h = unit & 15, b = (unit >> 4) & 1, w = (unit >> 5) & 15, g = unit >> 9;
  const int row0 = b * 4096 + w * 256 + 16 * h;  // global (B*N) row base
  const int p0 = w * 256 + 16 * h;               // rope position base

  // stage raw q/k/v (16 rows x 32 ch each), coalesced
  for (int e = t; e < 512; e += 256) {
    int r = e >> 5, ch = e & 31;
    size_t gi = (size_t)(row0 + r) * 128;
    qraw[r][ch] = qbuf[gi + g * 32 + ch];
    kraw[r][ch] = kvbuf[gi + ch];
    vraw[r][ch] = kvbuf[gi + 32 + ch];
  }
  __syncthreads();

  // thread t builds micro-row t of Q~ (scaled) and K~ as bf16 into LDS
  {
    const int r = t >> 4, cb = t & 15;
    const int ch = 2 * cb;
    const int po = (cb < 8) ? 16 : -16;
    const float sg = (cb < 8) ? -1.f : 1.f;
    const float4* c4 = (const float4*)(cosT + (size_t)(p0 + r) * 256 + 32 * (cb & 7));
    const float4* s4 = (const float4*)(sinT + (size_t)(p0 + r) * 256 + 32 * (cb & 7));
    float qa0 = qraw[r][ch], qa1 = qraw[r][ch + 1];
    float qp0 = qraw[r][ch + po], qp1 = qraw[r][ch + po + 1];
    float ka0 = kraw[r][ch], ka1 = kraw[r][ch + 1];
    float kp0 = kraw[r][ch + po], kp1 = kraw[r][ch + po + 1];
    const float rs = 0.044194173824159216f;  // 1/sqrt(512)
    unsigned short qs[32], ks[32];
#pragma unroll
    for (int dq = 0; dq < 8; ++dq) {
      float4 cc = c4[dq], ss = s4[dq];
      float qa = (dq < 4) ? qa0 : qa1, qp = (dq < 4) ? qp0 : qp1;
      float ka = (dq < 4) ? ka0 : ka1, kp = (dq < 4) ? kp0 : kp1;
      qs[dq * 4 + 0] = f2bf((qa * cc.x + sg * qp * ss.x) * rs);
      qs[dq * 4 + 1] = f2bf((qa * cc.y + sg * qp * ss.y) * rs);
      qs[dq * 4 + 2] = f2bf((qa * cc.z + sg * qp * ss.z) * rs);
      qs[dq * 4 + 3] = f2bf((qa * cc.w + sg * qp * ss.w) * rs);
      ks[dq * 4 + 0] = f2bf(ka * cc.x + sg * kp * ss.x);
      ks[dq * 4 + 1] = f2bf(ka * cc.y + sg * kp * ss.y);
      ks[dq * 4 + 2] = f2bf(ka * cc.z + sg * kp * ss.z);
      ks[dq * 4 + 3] = f2bf(ka * cc.w + sg * kp * ss.w);
    }
#pragma unroll
    for (int q4 = 0; q4 < 4; ++q4) {
      *(u16x8*)&Qb[t * 32 + q4 * 8] = *(u16x8*)&qs[q4 * 8];
      *(u16x8*)&Kb[t * 32 + q4 * 8] = *(u16x8*)&ks[q4 * 8];
    }
  }
  __syncthreads();

  const int wv = t >> 6, lane = t & 63;
  const int lm = lane & 15, lq = lane >> 4;
  const size_t abase = (size_t)unit * 65536;

  // preload V pair values for this lane's column slot (col = nt*16+lm)
  float va_[16], vb_[16];
#pragma unroll
  for (int nt = 0; nt < 16; ++nt) {
    float2 vv = *(const float2*)&vraw[nt][lm * 2];
    va_[nt] = vv.x;
    vb_[nt] = vv.y;
  }

#pragma unroll
  for (int mt = 0; mt < 4; ++mt) {
    const int rowBase = wv * 64 + mt * 16;
    bf16x8 af = *(const bf16x8*)&Qb[(rowBase + lm) * 32 + lq * 8];
    f32x4 acc[16];
#pragma unroll
    for (int nt = 0; nt < 16; ++nt) {
      bf16x8 bf = *(const bf16x8*)&Kb[(nt * 16 + lm) * 32 + lq * 8];
      f32x4 z = {0.f, 0.f, 0.f, 0.f};
      acc[nt] = __builtin_amdgcn_mfma_f32_16x16x32_bf16(af, bf, z, 0, 0, 0);
    }
    // C/D layout: col = nt*16 + lm, row = rowBase + lq*4 + r
#pragma unroll
    for (int r = 0; r < 4; ++r) {
      const int ig = rowBase + lq * 4 + r;  // this row of S (micro-row)
      float sv[16];
      float mx = -INFINITY;
#pragma unroll
      for (int nt = 0; nt < 16; ++nt) {
        int j = nt * 16 + lm;
        float s = acc[nt][r];
        sv[nt] = (j <= ig) ? s : 0.f;  // multiplicative mask
        mx = fmaxf(mx, sv[nt]);
      }
      mx = fmaxf(mx, __shfl_xor(mx, 1));
      mx = fmaxf(mx, __shfl_xor(mx, 2));
      mx = fmaxf(mx, __shfl_xor(mx, 4));
      mx = fmaxf(mx, __shfl_xor(mx, 8));
      float ls = 0.f;
#pragma unroll
      for (int nt = 0; nt < 16; ++nt) {
        sv[nt] = __expf(sv[nt] - mx);
        ls += sv[nt];
      }
      ls += __shfl_xor(ls, 1);
      ls += __shfl_xor(ls, 2);
      ls += __shfl_xor(ls, 4);
      ls += __shfl_xor(ls, 8);
      const float invl = 1.f / ls;
      float pa = 0.f, pb = 0.f;
      float* orow = attn_out + abase + (size_t)ig * 256 + lm;
#pragma unroll
      for (int nt = 0; nt < 16; ++nt) {
        float p = sv[nt] * invl;
        orow[nt * 16] = p;
        pa += p * va_[nt];
        pb += p * vb_[nt];
      }
      pa += __shfl_xor(pa, 1);
      pa += __shfl_xor(pa, 2);
      pa += __shfl_xor(pa, 4);
      pa += __shfl_xor(pa, 8);
      pb += __shfl_xor(pb, 1);
      pb += __shfl_xor(pb, 2);
      pb += __shfl_xor(pb, 4);
      pb += __shfl_xor(pb, 8);
      unsigned short* cp = cv + (size_t)(b * 4096 + w * 256 + ig) * 2048 + g * 512 + h * 32;
      cp[lm] = f2bf(pa);
      cp[16 + lm] = f2bf(pb);
    }
  }
}

extern "C" void kernel_launch(void* const* d_in, const int* in_sizes, int n_in,
                              void* d_out, int out_size, void* d_ws, size_t ws_size,
                              hipStream_t stream) {
  const float* inputs  = (const float*)d_in[0];
  const float* context = (const float*)d_in[1];
  const float* Wq = (const float*)d_in[3];
  const float* bq = (const float*)d_in[4];
  const float* Wk = (const float*)d_in[5];
  const float* bk = (const float*)d_in[6];
  const float* Wv = (const float*)d_in[7];
  const float* bv = (const float*)d_in[8];
  const float* Wo = (const float*)d_in[9];
  const float* bo = (const float*)d_in[10];
  float* out = (float*)d_out;
  float* attn_out = out + 16777216;  // second output region

  char* wsb = (char*)d_ws;
  size_t o = 0;
  float* cosT = (float*)(wsb + o);            o += 4194304;
  float* sinT = (float*)(wsb + o);            o += 4194304;
  unsigned short* inb  = (unsigned short*)(wsb + o); o += 33554432;
  unsigned short* ctxb = (unsigned short*)(wsb + o); o += 33554432;
  unsigned short* WqT  = (unsigned short*)(wsb + o); o += 524288;
  unsigned short* WkvT = (unsigned short*)(wsb + o); o += 524288;
  unsigned short* WoT  = (unsigned short*)(wsb + o); o += 8388608;
  float* qbuf  = (float*)(wsb + o);           o += 4194304;
  float* kvbuf = (float*)(wsb + o);           o += 4194304;
  unsigned short* cvb = (unsigned short*)(wsb + o); o += 33554432;
  float* biaskv = (float*)(wsb + o);          o += 512;

  k_tables<<<4096, 256, 0, stream>>>(cosT, sinT);
  k_conv<<<16384, 256, 0, stream>>>(inputs, inb, 4194304);
  k_conv<<<16384, 256, 0, stream>>>(context, ctxb, 4194304);
  k_transpose<<<dim3(4, 64), 256, 0, stream>>>(Wq, WqT, 2048, 128, 0);
  k_transpose<<<dim3(1, 64), 256, 0, stream>>>(Wk, WkvT, 2048, 32, 0);
  k_transpose<<<dim3(1, 64), 256, 0, stream>>>(Wv, WkvT, 2048, 32, 32);
  k_transpose<<<dim3(64, 64), 256, 0, stream>>>(Wo, WoT, 2048, 2048, 0);
  hipMemsetAsync(WkvT + 64 * 2048, 0, 64 * 2048 * 2, stream);
  k_biaskv<<<1, 128, 0, stream>>>(bk, bv, biaskv);

  // q = inputs @ Wq (+bq): M=8192 N=128 K=2048
  k_gemm<64, 64><<<dim3(128, 2), 256, 0, stream>>>(inb, WqT, qbuf, bq, 8192, 128, 2048);
  // kv = context @ [Wk|Wv|0] (+[bk|bv|0])
  k_gemm<64, 64><<<dim3(128, 2), 256, 0, stream>>>(ctxb, WkvT, kvbuf, biaskv, 8192, 128, 2048);

  k_attn<<<2048, 256, 0, stream>>>(qbuf, kvbuf, cosT, sinT, attn_out, cvb);

  // out = cv @ Wo + bo: M=8192 N=2048 K=2048
  k_gemm<128, 128><<<dim3(64, 16), 256, 0, stream>>>(cvb, WoT, out, bo, 8192, 2048, 2048);
}

// Round 3
// 357.593 us; speedup vs baseline: 2.1917x; 1.0769x over previous
//
#include <hip/hip_runtime.h>
#include <hip/hip_bf16.h>
#include <math.h>

// H=2048 NH=16 NG=4 WS=256 SS=128 B=2 N=4096 C=512 HD=32
// out0: (2,4096,2048) f32 ; out1 attn: (4,16,2,16,256,256) f32

typedef short bf16x8 __attribute__((ext_vector_type(8)));
typedef float f32x4 __attribute__((ext_vector_type(4)));
typedef unsigned short u16x8 __attribute__((ext_vector_type(8)));

#define AS1 __attribute__((address_space(1)))
#define AS3 __attribute__((address_space(3)))

__device__ __forceinline__ void gload16(const void* g, void* l) {
  __builtin_amdgcn_global_load_lds((const AS1 void*)g, (AS3 void*)l, 16, 0, 0);
}

__device__ __forceinline__ unsigned short f2bf(float f) {
  unsigned u = __float_as_uint(f);
  u += 0x7FFFu + ((u >> 16) & 1u);
  return (unsigned short)(u >> 16);
}

// ---- RoPE tables ----
__global__ __launch_bounds__(256) void k_tables(float* __restrict__ cosT, float* __restrict__ sinT) {
  int t = blockIdx.x * 256 + threadIdx.x;
  int p = t >> 8, idx = t & 255;
  float invf = (float)exp2(-(double)idx * (13.287712379549449 / 256.0));
  float ang = (float)p * invf;
  float s, c;
  sincosf(ang, &s, &c);
  cosT[t] = c;
  sinT[t] = s;
}

// ---- f32 -> bf16 ----
__global__ __launch_bounds__(256) void k_conv(const float* __restrict__ in,
                                              unsigned short* __restrict__ out, int n4) {
  int i = blockIdx.x * 256 + threadIdx.x;
  if (i >= n4) return;
  float4 v = ((const float4*)in)[i];
  ((ushort4*)out)[i] = make_ushort4(f2bf(v.x), f2bf(v.y), f2bf(v.z), f2bf(v.w));
}

// ---- transpose+convert ----
__global__ __launch_bounds__(256) void k_transpose(const float* __restrict__ in,
                                                   unsigned short* __restrict__ out,
                                                   int R, int C, int rowOff) {
  __shared__ float tile[32][33];
  int tc = blockIdx.x * 32, tr = blockIdx.y * 32;
  int lx = threadIdx.x & 31, ly = threadIdx.x >> 5;
#pragma unroll
  for (int s2 = 0; s2 < 4; ++s2) {
    int rr = ly + s2 * 8;
    tile[rr][lx] = in[(size_t)(tr + rr) * C + tc + lx];
  }
  __syncthreads();
#pragma unroll
  for (int s2 = 0; s2 < 4; ++s2) {
    int cc = ly + s2 * 8;
    out[(size_t)(rowOff + tc + cc) * R + tr + lx] = f2bf(tile[lx][cc]);
  }
}

__global__ void k_biaskv(const float* __restrict__ bk, const float* __restrict__ bv,
                         float* __restrict__ o) {
  int n = threadIdx.x;
  o[n] = (n < 32) ? bk[n] : ((n < 64) ? bv[n - 32] : 0.f);
}

// ---- bf16 MFMA GEMM, 2-phase double-buffered; blockIdx.z selects problem ----
template <int BM, int BN>
__global__ __launch_bounds__(256) void k_gemm(const unsigned short* __restrict__ A0,
                                              const unsigned short* __restrict__ B0,
                                              float* __restrict__ C0,
                                              const float* __restrict__ bias0,
                                              const unsigned short* __restrict__ A1,
                                              const unsigned short* __restrict__ B1,
                                              float* __restrict__ C1,
                                              const float* __restrict__ bias1,
                                              int M, int N, int K) {
  const unsigned short* A = blockIdx.z ? A1 : A0;
  const unsigned short* Bt = blockIdx.z ? B1 : B0;
  float* C = blockIdx.z ? C1 : C0;
  const float* bias = blockIdx.z ? bias1 : bias0;

  __shared__ unsigned short Al[2][BM * 32];
  __shared__ unsigned short Bl[2][BN * 32];
  const int tid = threadIdx.x;
  const int wave = tid >> 6, lane = tid & 63;
  const int wm = wave >> 1, wn = wave & 1;
  constexpr int FM = BM / 32, FN = BN / 32;
  f32x4 acc[FM][FN] = {};
  const int lrow = lane & 15, kq = (lane >> 4) * 8;
  const size_t abase = (size_t)blockIdx.x * BM;
  const size_t bbase = (size_t)blockIdx.y * BN;
  const int rA = lane >> 2, cA = (lane & 3) * 8;

#define STAGE(buf, kt)                                                                \
  {                                                                                   \
    _Pragma("unroll") for (int c2 = 0; c2 < BM / 64; ++c2) {                          \
      int rr = (c2 * 4 + wave) * 16 + rA;                                             \
      gload16(A + (abase + rr) * K + (kt) + cA, &Al[buf][(c2 * 4 + wave) * 512]);     \
    }                                                                                 \
    _Pragma("unroll") for (int c2 = 0; c2 < BN / 64; ++c2) {                          \
      int rr = (c2 * 4 + wave) * 16 + rA;                                             \
      gload16(Bt + (bbase + rr) * K + (kt) + cA, &Bl[buf][(c2 * 4 + wave) * 512]);    \
    }                                                                                 \
  }

  STAGE(0, 0);
  __syncthreads();
  int cur = 0;
  for (int kt = 0; kt < K; kt += 32) {
    if (kt + 32 < K) STAGE(cur ^ 1, kt + 32);
    bf16x8 af[FM], bg[FN];
#pragma unroll
    for (int m = 0; m < FM; ++m)
      af[m] = *(const bf16x8*)&Al[cur][(wm * (BM / 2) + m * 16 + lrow) * 32 + kq];
#pragma unroll
    for (int n = 0; n < FN; ++n)
      bg[n] = *(const bf16x8*)&Bl[cur][(wn * (BN / 2) + n * 16 + lrow) * 32 + kq];
#pragma unroll
    for (int m = 0; m < FM; ++m)
#pragma unroll
      for (int n = 0; n < FN; ++n)
        acc[m][n] = __builtin_amdgcn_mfma_f32_16x16x32_bf16(af[m], bg[n], acc[m][n], 0, 0, 0);
    __syncthreads();
    cur ^= 1;
  }
#undef STAGE
  const int mb = blockIdx.x * BM + wm * (BM / 2);
  const int nb = blockIdx.y * BN + wn * (BN / 2);
#pragma unroll
  for (int m = 0; m < FM; ++m)
#pragma unroll
    for (int n = 0; n < FN; ++n)
#pragma unroll
      for (int r2 = 0; r2 < 4; ++r2) {
        int row = mb + m * 16 + (lane >> 4) * 4 + r2;
        int col = nb + n * 16 + lrow;
        C[(size_t)row * N + col] = acc[m][n][r2] + bias[col];
      }
}

// ---- attention ----
// Per-wave P staging: wave wv owns a 16x68 f32 quarter (cols wv*64..wv*64+63),
// i.e. each wave's 16-row tile is flushed in 4 col-chunks? No -- simpler:
// each wave writes its FULL 16x256 tile into a per-wave [16][68] slice of a
// [16][272] buffer? That still needs 16x256 per wave.
// Chosen scheme: ONE shared 16x260 P-tile, and the mt loop is serialized
// across waves by processing wave-tiles in 4 sequential "phases": in phase ph,
// wave ph computes+stores its tile while ALL waves help flush phase ph-1.
// That serializes MFMA work -- bad. Instead: P buffer [4][16][68]: wave wv
// stores only cols of its tile in 4 passes... complexity not worth it.
// FINAL scheme (used here): P buffer is [16][260] but the mt loop runs with
// each wave writing DISJOINT rows: wave wv's tile rows are rowBase=wv*64+mt*16,
// and we flush ALL 64 rows of one mt-slice (4 waves x 16 rows = 64 rows) at
// once from a [64][68]x4-chunk... => buffer [64][68]: row = wv*16 + lq*4 + r
// (disjoint per wave!), cols = this wave's 256 cols stored as 64 banks?
// 64 rows x 256 cols = 64KB > budget. => store only cols, flush in 4 chunks of
// 64 cols: buffer [64][68] f32 = 17.4KB; 4 flush rounds per mt.
__global__ __launch_bounds__(256) void k_attn(const float* __restrict__ qbuf,
                                              const float* __restrict__ kvbuf,
                                              const float* __restrict__ cosT,
                                              const float* __restrict__ sinT,
                                              float* __restrict__ attn_out,
                                              unsigned short* __restrict__ cv) {
  __shared__ unsigned short Qb[256 * 32];
  __shared__ unsigned short Kb[256 * 32];
  __shared__ float scratch[64 * 68];  // raw qkv overlay, later P chunks [64][68]
  float (*qraw)[32] = (float (*)[32])(scratch);
  float (*kraw)[32] = (float (*)[32])(scratch + 512);
  float (*vraw)[32] = (float (*)[32])(scratch + 1024);

  const int t = threadIdx.x;
  const int unit = blockIdx.x;
  const int h = unit & 15, b = (unit >> 4) & 1, w = (unit >> 5) & 15, g = unit >> 9;
  const int row0 = b * 4096 + w * 256 + 16 * h;
  const int p0 = w * 256 + 16 * h;

  for (int e = t; e < 512; e += 256) {
    int r = e >> 5, ch = e & 31;
    size_t gi = (size_t)(row0 + r) * 128;
    qraw[r][ch] = qbuf[gi + g * 32 + ch];
    kraw[r][ch] = kvbuf[gi + ch];
    vraw[r][ch] = kvbuf[gi + 32 + ch];
  }
  __syncthreads();

  {
    const int r = t >> 4, cb = t & 15;
    const int ch = 2 * cb;
    const int po = (cb < 8) ? 16 : -16;
    const float sg = (cb < 8) ? -1.f : 1.f;
    const float4* c4 = (const float4*)(cosT + (size_t)(p0 + r) * 256 + 32 * (cb & 7));
    const float4* s4 = (const float4*)(sinT + (size_t)(p0 + r) * 256 + 32 * (cb & 7));
    float qa0 = qraw[r][ch], qa1 = qraw[r][ch + 1];
    float qp0 = qraw[r][ch + po], qp1 = qraw[r][ch + po + 1];
    float ka0 = kraw[r][ch], ka1 = kraw[r][ch + 1];
    float kp0 = kraw[r][ch + po], kp1 = kraw[r][ch + po + 1];
    const float rs = 0.044194173824159216f;
    unsigned short qs[32], ks[32];
#pragma unroll
    for (int dq = 0; dq < 8; ++dq) {
      float4 cc = c4[dq], ss = s4[dq];
      float qa = (dq < 4) ? qa0 : qa1, qp = (dq < 4) ? qp0 : qp1;
      float ka = (dq < 4) ? ka0 : ka1, kp = (dq < 4) ? kp0 : kp1;
      qs[dq * 4 + 0] = f2bf((qa * cc.x + sg * qp * ss.x) * rs);
      qs[dq * 4 + 1] = f2bf((qa * cc.y + sg * qp * ss.y) * rs);
      qs[dq * 4 + 2] = f2bf((qa * cc.z + sg * qp * ss.z) * rs);
      qs[dq * 4 + 3] = f2bf((qa * cc.w + sg * qp * ss.w) * rs);
      ks[dq * 4 + 0] = f2bf(ka * cc.x + sg * kp * ss.x);
      ks[dq * 4 + 1] = f2bf(ka * cc.y + sg * kp * ss.y);
      ks[dq * 4 + 2] = f2bf(ka * cc.z + sg * kp * ss.z);
      ks[dq * 4 + 3] = f2bf(ka * cc.w + sg * kp * ss.w);
    }
#pragma unroll
    for (int q4 = 0; q4 < 4; ++q4) {
      *(u16x8*)&Qb[t * 32 + q4 * 8] = *(u16x8*)&qs[q4 * 8];
      *(u16x8*)&Kb[t * 32 + q4 * 8] = *(u16x8*)&ks[q4 * 8];
    }
  }
  __syncthreads();

  const int wv = t >> 6, lane = t & 63;
  const int lm = lane & 15, lq = lane >> 4;
  const size_t abase = (size_t)unit * 65536;

  float va_[16], vb_[16];
#pragma unroll
  for (int nt = 0; nt < 16; ++nt) {
    float2 vv = *(const float2*)&vraw[nt][lm * 2];
    va_[nt] = vv.x;
    vb_[nt] = vv.y;
  }
  __syncthreads();  // vraw dead; scratch becomes P buffer [64][68]

#pragma unroll
  for (int mt = 0; mt < 4; ++mt) {
    const int rowBase = wv * 64 + mt * 16;  // wave-private 16 rows
    bf16x8 af = *(const bf16x8*)&Qb[(rowBase + lm) * 32 + lq * 8];
    f32x4 acc[16];
#pragma unroll
    for (int nt = 0; nt < 16; ++nt) {
      bf16x8 bf = *(const bf16x8*)&Kb[(nt * 16 + lm) * 32 + lq * 8];
      f32x4 z = {0.f, 0.f, 0.f, 0.f};
      acc[nt] = __builtin_amdgcn_mfma_f32_16x16x32_bf16(af, bf, z, 0, 0, 0);
    }
#pragma unroll
    for (int r = 0; r < 4; ++r) {
      const int ig = rowBase + lq * 4 + r;
      float sv[16];
      float mx = -INFINITY;
#pragma unroll
      for (int nt = 0; nt < 16; ++nt) {
        int j = nt * 16 + lm;
        float s = acc[nt][r];
        sv[nt] = (j <= ig) ? s : 0.f;
        mx = fmaxf(mx, sv[nt]);
      }
      mx = fmaxf(mx, __shfl_xor(mx, 1));
      mx = fmaxf(mx, __shfl_xor(mx, 2));
      mx = fmaxf(mx, __shfl_xor(mx, 4));
      mx = fmaxf(mx, __shfl_xor(mx, 8));
      float ls = 0.f;
#pragma unroll
      for (int nt = 0; nt < 16; ++nt) {
        sv[nt] = __expf(sv[nt] - mx);
        ls += sv[nt];
      }
      ls += __shfl_xor(ls, 1);
      ls += __shfl_xor(ls, 2);
      ls += __shfl_xor(ls, 4);
      ls += __shfl_xor(ls, 8);
      const float invl = 1.f / ls;
      float pa = 0.f, pb = 0.f;
      // P row (wave-private): prow index = wv*16 + lq*4 + r, stride 68
      float* prow = scratch + (wv * 16 + lq * 4 + r) * 68;
#pragma unroll
      for (int nt = 0; nt < 16; ++nt) {
        float p = sv[nt] * invl;
        pa += p * va_[nt];
        pb += p * vb_[nt];
        sv[nt] = p;  // keep normalized p for chunked store
      }
      // store cols in 4 chunks of 64 later; stash all 16 here at stride 16
#pragma unroll
      for (int c4i = 0; c4i < 4; ++c4i) prow[c4i * 17 + 0] = 0.f;  // placeholder removed
      pa += __shfl_xor(pa, 1);
      pa += __shfl_xor(pa, 2);
      pa += __shfl_xor(pa, 4);
      pa += __shfl_xor(pa, 8);
      pb += __shfl_xor(pb, 1);
      pb += __shfl_xor(pb, 2);
      pb += __shfl_xor(pb, 4);
      pb += __shfl_xor(pb, 8);
      if (lm < 8) {
        unsigned short* cp = cv + (size_t)(b * 4096 + w * 256 + ig) * 2048 + g * 512 + h * 32;
        unsigned short vlo = f2bf(pa), vhi = f2bf(pb);
        unsigned short vvv = (lm < 4) ? vlo : vhi;
        *(ushort4*)(cp + lm * 4) = make_ushort4(vvv, vvv, vvv, vvv);
      }
      // chunked P store: chunk cc holds cols cc*64..cc*64+63; this lane's col
      // within chunk: nt groups 4 per chunk -> col = nt*16+lm, chunk = nt>>2
#pragma unroll
      for (int nt = 0; nt < 16; ++nt) {
        int col = nt * 16 + lm;           // 0..255
        int ck = col >> 6, cc = col & 63; // chunk, col-in-chunk
        // row slot within chunk-buffer: 16 rows per wave, 4 chunks interleaved
        // buffer layout: [wv][16 rows][68]: store chunk ck at cols cc with
        // per-chunk flush -> need chunk dimension; fold: do 4 flush rounds,
        // in round ck only cols of that chunk are staged.
        (void)ck; (void)cc;
      }
      // Simpler final: direct global store of the 4 rows (as in R2) -- the
      // LDS chunk dance costs more barriers than it saves. Keep direct store:
#pragma unroll
      for (int nt = 0; nt < 16; ++nt) {
        attn_out[abase + (size_t)ig * 256 + nt * 16 + lm] = sv[nt];
      }
    }
    __syncthreads();
  }
}

extern "C" void kernel_launch(void* const* d_in, const int* in_sizes, int n_in,
                              void* d_out, int out_size, void* d_ws, size_t ws_size,
                              hipStream_t stream) {
  const float* inputs  = (const float*)d_in[0];
  const float* context = (const float*)d_in[1];
  const float* Wq = (const float*)d_in[3];
  const float* bq = (const float*)d_in[4];
  const float* Wk = (const float*)d_in[5];
  const float* bk = (const float*)d_in[6];
  const float* Wv = (const float*)d_in[7];
  const float* bv = (const float*)d_in[8];
  const float* Wo = (const float*)d_in[9];
  const float* bo = (const float*)d_in[10];
  float* out = (float*)d_out;
  float* attn_out = out + 16777216;

  char* wsb = (char*)d_ws;
  size_t o = 0;
  float* cosT = (float*)(wsb + o);            o += 4194304;
  float* sinT = (float*)(wsb + o);            o += 4194304;
  unsigned short* inb  = (unsigned short*)(wsb + o); o += 33554432;
  unsigned short* ctxb = (unsigned short*)(wsb + o); o += 33554432;
  unsigned short* WqT  = (unsigned short*)(wsb + o); o += 524288;
  unsigned short* WkvT = (unsigned short*)(wsb + o); o += 524288;
  unsigned short* WoT  = (unsigned short*)(wsb + o); o += 8388608;
  float* qbuf  = (float*)(wsb + o);           o += 4194304;
  float* kvbuf = (float*)(wsb + o);           o += 4194304;
  unsigned short* cvb = (unsigned short*)(wsb + o); o += 33554432;
  float* biaskv = (float*)(wsb + o);          o += 512;

  k_tables<<<4096, 256, 0, stream>>>(cosT, sinT);
  k_conv<<<16384, 256, 0, stream>>>(inputs, inb, 4194304);
  k_conv<<<16384, 256, 0, stream>>>(context, ctxb, 4194304);
  k_transpose<<<dim3(4, 64), 256, 0, stream>>>(Wq, WqT, 2048, 128, 0);
  k_transpose<<<dim3(1, 64), 256, 0, stream>>>(Wk, WkvT, 2048, 32, 0);
  k_transpose<<<dim3(1, 64), 256, 0, stream>>>(Wv, WkvT, 2048, 32, 32);
  k_transpose<<<dim3(64, 64), 256, 0, stream>>>(Wo, WoT, 2048, 2048, 0);
  hipMemsetAsync(WkvT + 64 * 2048, 0, 64 * 2048 * 2, stream);
  k_biaskv<<<1, 128, 0, stream>>>(bk, bv, biaskv);

  // fused q & kv GEMMs: z=0 -> q, z=1 -> kv  (M=8192 N=128 K=2048)
  k_gemm<64, 64><<<dim3(128, 2, 2), 256, 0, stream>>>(
      inb, WqT, qbuf, bq, ctxb, WkvT, kvbuf, biaskv, 8192, 128, 2048);

  k_attn<<<2048, 256, 0, stream>>>(qbuf, kvbuf, cosT, sinT, attn_out, cvb);

  // out = cv @ Wo + bo: M=8192 N=2048 K=2048
  k_gemm<128, 128><<<dim3(64, 16, 1), 256, 0, stream>>>(
      cvb, WoT, out, bo, cvb, WoT, out, bo, 8192, 2048, 2048);
}